// Round 12
// baseline (107.528 us; speedup 1.0000x reference)
//
#include <hip/hip_runtime.h>
#include <hip/hip_bf16.h>
#include <hip/hip_fp16.h>

// GCN 2-layer: N=50000 nodes, E=800000 edges, 128->128(relu)->64.
// CSR build: two-level LDS-binned partition (128-node buckets). GEMMs: fp16
// MFMA 16x16x32, LDS-free, prepacked W, dinv-free (h unscaled); gemm1 fused
// into the hist launch (independent of CSR build). Aggs gather dinv[src]
// per edge (L2-resident table) via width-32 shuffle broadcast.

#define CHUNK 4096   // edges per partition chunk
#define BSHIFT 7
#define BSIZE 128    // nodes per bucket
#define BCAP 4096    // max edges per bucket held in LDS (avg ~2046)

typedef unsigned int uint;
typedef _Float16 f16x8 __attribute__((ext_vector_type(8)));
typedef float f32x4 __attribute__((ext_vector_type(4)));

__device__ __forceinline__ float2 h2f(uint v) {
  __half2 h;
  __builtin_memcpy(&h, &v, 4);
  return __half22float2(h);
}

__device__ __forceinline__ uint f2h(float a, float b) {
  __half2 h = __halves2half2(__float2half_rn(a), __float2half_rn(b));
  uint r;
  __builtin_memcpy(&r, &h, 4);
  return r;
}

// int64-vs-int32 detection per block: wave-0 ballot over first 64 high words.
__device__ __forceinline__ int block_is64(const int* ei, int* s_is64) {
  if (threadIdx.x < 64) {
    unsigned long long m = __ballot(ei[2 * threadIdx.x + 1] != 0);
    if (threadIdx.x == 0) *s_is64 = (m == 0ULL) ? 1 : 0;
  }
  __syncthreads();
  return *s_is64;
}

// ---- prep: W packs (fragment-linear fp16) + zero totals ----
__global__ void prep_k(const float* __restrict__ W1,
                       const float* __restrict__ W2,
                       _Float16* __restrict__ P,
                       int* __restrict__ totals, int nbuck) {
  int li = blockIdx.x * 256 + threadIdx.x;  // 0..24575
  if (li < nbuck) totals[li] = 0;
  if (li >= 24576) return;
  const float* W;
  _Float16* dst;
  int NC, idx;
  if (li < 16384) { W = W1; dst = P;         NC = 128; idx = li; }
  else            { W = W2; dst = P + 16384; NC = 64;  idx = li - 16384; }
  int NF = NC >> 4;
  int j = idx & 7;
  int l = (idx >> 3) & 63;
  int rest = idx >> 9;
  int c = rest % NF;
  int t = rest / NF;
  int k = t * 32 + ((l >> 4) << 3) + j;
  int col = c * 16 + (l & 15);
  dst[idx] = (_Float16)W[(size_t)k * NC + col];
}

// ---- shared MFMA GEMM body: H(fp16 row-major) = X[M,128] @ W[128,NC] ----
template <int NC, bool A16>
__device__ __forceinline__ void gemm_body(const void* __restrict__ Xv,
                                          const _Float16* __restrict__ Wp,
                                          _Float16* __restrict__ H,
                                          int M, int blk) {
  constexpr int NF = NC / 16;
  int lane = threadIdx.x & 63;
  int w = threadIdx.x >> 6;
  int row0 = blk * 64 + w * 16;
  int arow = row0 + (lane & 15);
  bool av = arow < M;
  const uint4* wp = (const uint4*)Wp;

  f32x4 acc[NF];
#pragma unroll
  for (int c = 0; c < NF; ++c) acc[c] = (f32x4){0.f, 0.f, 0.f, 0.f};

#pragma unroll
  for (int t = 0; t < 4; ++t) {
    f16x8 a;
    if constexpr (A16) {
      const _Float16* xr = (const _Float16*)Xv + (size_t)arow * 128 + ((lane >> 4) << 3);
      uint4 araw = av ? *(const uint4*)(xr + t * 32) : make_uint4(0u, 0u, 0u, 0u);
      __builtin_memcpy(&a, &araw, 16);
    } else {
      const float* xr = (const float*)Xv + (size_t)arow * 128 + ((lane >> 4) << 3);
      float4 lo = av ? *(const float4*)(xr + t * 32) : make_float4(0.f, 0.f, 0.f, 0.f);
      float4 hi = av ? *(const float4*)(xr + t * 32 + 4) : make_float4(0.f, 0.f, 0.f, 0.f);
      a[0] = (_Float16)lo.x; a[1] = (_Float16)lo.y;
      a[2] = (_Float16)lo.z; a[3] = (_Float16)lo.w;
      a[4] = (_Float16)hi.x; a[5] = (_Float16)hi.y;
      a[6] = (_Float16)hi.z; a[7] = (_Float16)hi.w;
    }
#pragma unroll
    for (int c = 0; c < NF; ++c) {
      uint4 braw = wp[(t * NF + c) * 64 + lane];
      f16x8 b;
      __builtin_memcpy(&b, &braw, 16);
      acc[c] = __builtin_amdgcn_mfma_f32_16x16x32_f16(a, b, acc[c], 0, 0, 0);
    }
  }

  int rbase = row0 + ((lane >> 4) << 2);
#pragma unroll
  for (int r = 0; r < 4; ++r) {
    int row = rbase + r;
    if (row < M) {
#pragma unroll
      for (int c = 0; c < NF; ++c)
        H[(size_t)row * NC + c * 16 + (lane & 15)] = (_Float16)acc[c][r];
    }
  }
}

// ---- fused launch: blocks [0,GB) = gemm1 (x @ W1 -> h1 fp16, unscaled);
//      blocks [GB, GB+nchunk) = per-chunk histogram (+atomic totals) ----
__global__ __launch_bounds__(256) void gemm1_hist_k(const float* __restrict__ x,
                                                    const _Float16* __restrict__ pW1,
                                                    _Float16* __restrict__ h1,
                                                    const int* __restrict__ ei,
                                                    int* __restrict__ gh,
                                                    int* __restrict__ totals,
                                                    int M, int E, int GB,
                                                    int nchunk, int nbuck) {
  if ((int)blockIdx.x < GB) {
    gemm_body<128, false>(x, pW1, h1, M, blockIdx.x);
    return;
  }
  __shared__ int h[512];
  __shared__ int s_is64;
  int c = blockIdx.x - GB;
  for (int i = threadIdx.x; i < 512; i += 256) h[i] = 0;
  int is64 = block_is64(ei, &s_is64);  // includes __syncthreads
  int base = c * CHUNK;
  int lim = min(CHUNK, E - base);
  for (int i = threadIdx.x; i < lim; i += 256) {
    int e = base + i;
    int d = is64 ? ei[2 * ((size_t)E + e)] : ei[(size_t)E + e];
    atomicAdd(&h[d >> BSHIFT], 1);
  }
  __syncthreads();
  for (int k = threadIdx.x; k < nbuck; k += 256) {
    gh[k * nchunk + c] = h[k];
    atomicAdd(&totals[k], h[k]);
  }
}

// A2: block k: bucketStart[k] (= sum totals[<k]) + scan of gh row k -> gbase.
__global__ __launch_bounds__(256) void scanrow_k(const int* __restrict__ gh,
                                                 const int* __restrict__ totals,
                                                 int* __restrict__ gbase,
                                                 int* __restrict__ bucketStart,
                                                 int* __restrict__ offsets,
                                                 int nchunk, int nbuck, int N, int E) {
  __shared__ int st[256];
  int k = blockIdx.x;
  int t = threadIdx.x;
  int partial = 0;
  for (int i = t; i < k; i += 256) partial += totals[i];
  st[t] = partial;
  __syncthreads();
  for (int o = 128; o > 0; o >>= 1) {
    if (t < o) st[t] += st[t + o];
    __syncthreads();
  }
  int bs = st[0];
  if (t == 0) {
    bucketStart[k] = bs;
    if (k == nbuck - 1) { bucketStart[nbuck] = E; offsets[N] = E; }
  }
  __syncthreads();
  int x = (t < nchunk) ? gh[k * nchunk + t] : 0;
  st[t] = x;
  __syncthreads();
  int incl = x;
  for (int o = 1; o < 256; o <<= 1) {
    int add = (t >= o) ? st[t - o] : 0;
    __syncthreads();
    incl += add;
    st[t] = incl;
    __syncthreads();
  }
  if (t < nchunk) gbase[k * nchunk + t] = bs + (incl - x);
}

// A3: partition edges into bucket-grouped tmp, packed (src16 | dstlow7<<16)
__global__ __launch_bounds__(256) void part_k(const int* __restrict__ ei,
                                              const int* __restrict__ gbase,
                                              int* __restrict__ tmp,
                                              int E, int nchunk, int nbuck) {
  __shared__ int cur[512];
  __shared__ int s_is64;
  int c = blockIdx.x;
  for (int i = threadIdx.x; i < nbuck; i += 256) cur[i] = gbase[i * nchunk + c];
  int is64 = block_is64(ei, &s_is64);
  int base = c * CHUNK;
  int lim = min(CHUNK, E - base);
  for (int i = threadIdx.x; i < lim; i += 256) {
    int e = base + i;
    int s, d;
    if (is64) {
      s = ei[2 * (size_t)e];
      d = ei[2 * ((size_t)E + e)];
    } else {
      s = ei[e];
      d = ei[(size_t)E + e];
    }
    int p = atomicAdd(&cur[d >> BSHIFT], 1);
    tmp[p] = s | ((d & (BSIZE - 1)) << 16);
  }
}

// B: one block per 128-node bucket: LDS count+scan -> offsets, dinv, csr_src
__global__ __launch_bounds__(256) void bucket_k(const int* __restrict__ tmp,
                                                const int* __restrict__ bucketStart,
                                                int* __restrict__ csr_src,
                                                int* __restrict__ offsets,
                                                float* __restrict__ dinv,
                                                int N) {
  __shared__ int ebuf[BCAP];
  __shared__ int cnt[BSIZE];
  __shared__ int st[256];
  __shared__ int lofs[BSIZE];
  int k = blockIdx.x;
  int b0 = bucketStart[k], b1 = bucketStart[k + 1];
  int sz = b1 - b0;
  int t = threadIdx.x;
  if (t < BSIZE) cnt[t] = 0;
  __syncthreads();
  bool inlds = (sz <= BCAP);
  if (inlds) {
    for (int i = t; i < sz; i += 256) {
      int v = tmp[b0 + i];
      ebuf[i] = v;
      atomicAdd(&cnt[v >> 16], 1);
    }
  } else {
    for (int i = t; i < sz; i += 256) atomicAdd(&cnt[tmp[b0 + i] >> 16], 1);
  }
  __syncthreads();
  int x = (t < BSIZE) ? cnt[t] : 0;
  st[t] = x;
  __syncthreads();
  int incl = x;
  for (int o = 1; o < 256; o <<= 1) {
    int add = (t >= o) ? st[t - o] : 0;
    __syncthreads();
    incl += add;
    st[t] = incl;
    __syncthreads();
  }
  int node = (k << BSHIFT) + t;
  if (t < BSIZE) {
    lofs[t] = incl - x;
    if (node < N) {
      offsets[node] = b0 + lofs[t];
      dinv[node] = rsqrtf((float)(x + 1));  // +1 self-loop
    }
  }
  __syncthreads();
  if (t < BSIZE) cnt[t] = lofs[t];  // reuse as cursor
  __syncthreads();
  if (inlds) {
    for (int i = t; i < sz; i += 256) {
      int v = ebuf[i];
      int p = atomicAdd(&cnt[v >> 16], 1);
      csr_src[b0 + p] = v & 0xFFFF;
    }
  } else {
    for (int i = t; i < sz; i += 256) {
      int v = tmp[b0 + i];
      int p = atomicAdd(&cnt[v >> 16], 1);
      csr_src[b0 + p] = v & 0xFFFF;
    }
  }
}

// ---- gemm2 standalone: h2(fp16, unscaled) = y @ W2 ----
__global__ __launch_bounds__(256) void gemm2_k(const _Float16* __restrict__ y,
                                               const _Float16* __restrict__ pW2,
                                               _Float16* __restrict__ h2, int M) {
  gemm_body<64, true>(y, pW2, h2, M, blockIdx.x);
}

// ---- agg1: y[i](fp16) = relu( dinv_i*(sum dinv_s h_s + dinv_i h_i) + b1 ) ----
// h rows: 32 uint2 (fp16x4) = 256B, UNscaled. One 32-lane segment per node.
// dinv[src] gathered once per edge (L2-resident), broadcast with the index.
__global__ __launch_bounds__(256) void agg1_k(const uint2* __restrict__ hp,
                                              const float* __restrict__ dinv,
                                              const int* __restrict__ offsets,
                                              const int* __restrict__ csr_src,
                                              const float* __restrict__ b,
                                              uint2* __restrict__ y, int n) {
  int wv = threadIdx.x >> 6;
  int lane = threadIdx.x & 63;
  int half = lane >> 5;
  int fl = lane & 31;
  int node = blockIdx.x * 8 + wv * 2 + half;
  if (node >= n) return;  // uniform within segment
  int beg = offsets[node], end = offsets[node + 1];
  int deg = end - beg;
  float di = dinv[node];
  uint2 su = hp[(size_t)node * 32 + fl];
  float2 sl = h2f(su.x), sh = h2f(su.y);
  float a0 = di * sl.x, a1 = di * sl.y, a2 = di * sh.x, a3 = di * sh.y;
  int sv = 0;
  float dv = 0.f;
  if (fl < deg) { sv = csr_src[beg + fl]; dv = dinv[sv]; }
  int lim = deg < 32 ? deg : 32;
  int e = 0;
  for (; e + 8 <= lim; e += 8) {
    int sA = __shfl(sv, e + 0, 32), sB = __shfl(sv, e + 1, 32);
    int sC = __shfl(sv, e + 2, 32), sD = __shfl(sv, e + 3, 32);
    int sE = __shfl(sv, e + 4, 32), sF = __shfl(sv, e + 5, 32);
    int sG = __shfl(sv, e + 6, 32), sH = __shfl(sv, e + 7, 32);
    float dA = __shfl(dv, e + 0, 32), dB = __shfl(dv, e + 1, 32);
    float dC = __shfl(dv, e + 2, 32), dD = __shfl(dv, e + 3, 32);
    float dE = __shfl(dv, e + 4, 32), dF = __shfl(dv, e + 5, 32);
    float dG = __shfl(dv, e + 6, 32), dH = __shfl(dv, e + 7, 32);
    uint2 uA = hp[(size_t)sA * 32 + fl];
    uint2 uB = hp[(size_t)sB * 32 + fl];
    uint2 uC = hp[(size_t)sC * 32 + fl];
    uint2 uD = hp[(size_t)sD * 32 + fl];
    uint2 uE = hp[(size_t)sE * 32 + fl];
    uint2 uF = hp[(size_t)sF * 32 + fl];
    uint2 uG = hp[(size_t)sG * 32 + fl];
    uint2 uH = hp[(size_t)sH * 32 + fl];
    float2 lA = h2f(uA.x), hA = h2f(uA.y), lB = h2f(uB.x), hB = h2f(uB.y);
    float2 lC = h2f(uC.x), hC = h2f(uC.y), lD = h2f(uD.x), hD = h2f(uD.y);
    float2 lE = h2f(uE.x), hE = h2f(uE.y), lF = h2f(uF.x), hF = h2f(uF.y);
    float2 lG = h2f(uG.x), hG = h2f(uG.y), lH = h2f(uH.x), hH = h2f(uH.y);
    a0 = fmaf(dA, lA.x, a0); a1 = fmaf(dA, lA.y, a1);
    a2 = fmaf(dA, hA.x, a2); a3 = fmaf(dA, hA.y, a3);
    a0 = fmaf(dB, lB.x, a0); a1 = fmaf(dB, lB.y, a1);
    a2 = fmaf(dB, hB.x, a2); a3 = fmaf(dB, hB.y, a3);
    a0 = fmaf(dC, lC.x, a0); a1 = fmaf(dC, lC.y, a1);
    a2 = fmaf(dC, hC.x, a2); a3 = fmaf(dC, hC.y, a3);
    a0 = fmaf(dD, lD.x, a0); a1 = fmaf(dD, lD.y, a1);
    a2 = fmaf(dD, hD.x, a2); a3 = fmaf(dD, hD.y, a3);
    a0 = fmaf(dE, lE.x, a0); a1 = fmaf(dE, lE.y, a1);
    a2 = fmaf(dE, hE.x, a2); a3 = fmaf(dE, hE.y, a3);
    a0 = fmaf(dF, lF.x, a0); a1 = fmaf(dF, lF.y, a1);
    a2 = fmaf(dF, hF.x, a2); a3 = fmaf(dF, hF.y, a3);
    a0 = fmaf(dG, lG.x, a0); a1 = fmaf(dG, lG.y, a1);
    a2 = fmaf(dG, hG.x, a2); a3 = fmaf(dG, hG.y, a3);
    a0 = fmaf(dH, lH.x, a0); a1 = fmaf(dH, lH.y, a1);
    a2 = fmaf(dH, hH.x, a2); a3 = fmaf(dH, hH.y, a3);
  }
  for (; e < lim; ++e) {
    int s = __shfl(sv, e, 32);
    float dd = __shfl(dv, e, 32);
    uint2 u = hp[(size_t)s * 32 + fl];
    float2 l = h2f(u.x), h = h2f(u.y);
    a0 = fmaf(dd, l.x, a0); a1 = fmaf(dd, l.y, a1);
    a2 = fmaf(dd, h.x, a2); a3 = fmaf(dd, h.y, a3);
  }
  for (int ee = beg + 32; ee < end; ++ee) {  // deg>32 fallback (rare, uniform)
    int s = csr_src[ee];
    float dd = dinv[s];
    uint2 u = hp[(size_t)s * 32 + fl];
    float2 l = h2f(u.x), h = h2f(u.y);
    a0 = fmaf(dd, l.x, a0); a1 = fmaf(dd, l.y, a1);
    a2 = fmaf(dd, h.x, a2); a3 = fmaf(dd, h.y, a3);
  }
  float4 bb = *(const float4*)(b + 4 * fl);
  float o0 = fmaxf(fmaf(di, a0, bb.x), 0.f);
  float o1 = fmaxf(fmaf(di, a1, bb.y), 0.f);
  float o2 = fmaxf(fmaf(di, a2, bb.z), 0.f);
  float o3 = fmaxf(fmaf(di, a3, bb.w), 0.f);
  uint2 o;
  o.x = f2h(o0, o1);
  o.y = f2h(o2, o3);
  y[(size_t)node * 32 + fl] = o;
}

// ---- agg2: out[i](f32) = dinv_i*(sum dinv_s h_s + dinv_i h_i) + b2, 64 f ----
// h rows: 32 uints (fp16x2) = 128B, UNscaled. One 32-lane segment per node.
__global__ __launch_bounds__(256) void agg2_k(const uint* __restrict__ hp,
                                              const float* __restrict__ dinv,
                                              const int* __restrict__ offsets,
                                              const int* __restrict__ csr_src,
                                              const float* __restrict__ b,
                                              float* __restrict__ out, int n) {
  int wv = threadIdx.x >> 6;
  int lane = threadIdx.x & 63;
  int half = lane >> 5;
  int fl = lane & 31;
  int node = blockIdx.x * 8 + wv * 2 + half;
  if (node >= n) return;
  int beg = offsets[node], end = offsets[node + 1];
  int deg = end - beg;
  float di = dinv[node];
  float2 self = h2f(hp[(size_t)node * 32 + fl]);
  float ax = di * self.x, ay = di * self.y;
  int sv = 0;
  float dv = 0.f;
  if (fl < deg) { sv = csr_src[beg + fl]; dv = dinv[sv]; }
  int lim = deg < 32 ? deg : 32;
  int e = 0;
  for (; e + 8 <= lim; e += 8) {
    int s0 = __shfl(sv, e + 0, 32), s1 = __shfl(sv, e + 1, 32);
    int s2 = __shfl(sv, e + 2, 32), s3 = __shfl(sv, e + 3, 32);
    int s4 = __shfl(sv, e + 4, 32), s5 = __shfl(sv, e + 5, 32);
    int s6 = __shfl(sv, e + 6, 32), s7 = __shfl(sv, e + 7, 32);
    float d0 = __shfl(dv, e + 0, 32), d1 = __shfl(dv, e + 1, 32);
    float d2 = __shfl(dv, e + 2, 32), d3 = __shfl(dv, e + 3, 32);
    float d4 = __shfl(dv, e + 4, 32), d5 = __shfl(dv, e + 5, 32);
    float d6 = __shfl(dv, e + 6, 32), d7 = __shfl(dv, e + 7, 32);
    uint u0 = hp[(size_t)s0 * 32 + fl];
    uint u1 = hp[(size_t)s1 * 32 + fl];
    uint u2 = hp[(size_t)s2 * 32 + fl];
    uint u3 = hp[(size_t)s3 * 32 + fl];
    uint u4 = hp[(size_t)s4 * 32 + fl];
    uint u5 = hp[(size_t)s5 * 32 + fl];
    uint u6 = hp[(size_t)s6 * 32 + fl];
    uint u7 = hp[(size_t)s7 * 32 + fl];
    float2 v0 = h2f(u0), v1 = h2f(u1), v2 = h2f(u2), v3 = h2f(u3);
    float2 v4 = h2f(u4), v5 = h2f(u5), v6 = h2f(u6), v7 = h2f(u7);
    ax = fmaf(d0, v0.x, ax); ay = fmaf(d0, v0.y, ay);
    ax = fmaf(d1, v1.x, ax); ay = fmaf(d1, v1.y, ay);
    ax = fmaf(d2, v2.x, ax); ay = fmaf(d2, v2.y, ay);
    ax = fmaf(d3, v3.x, ax); ay = fmaf(d3, v3.y, ay);
    ax = fmaf(d4, v4.x, ax); ay = fmaf(d4, v4.y, ay);
    ax = fmaf(d5, v5.x, ax); ay = fmaf(d5, v5.y, ay);
    ax = fmaf(d6, v6.x, ax); ay = fmaf(d6, v6.y, ay);
    ax = fmaf(d7, v7.x, ax); ay = fmaf(d7, v7.y, ay);
  }
  for (; e < lim; ++e) {
    int s = __shfl(sv, e, 32);
    float dd = __shfl(dv, e, 32);
    float2 v = h2f(hp[(size_t)s * 32 + fl]);
    ax = fmaf(dd, v.x, ax);
    ay = fmaf(dd, v.y, ay);
  }
  for (int ee = beg + 32; ee < end; ++ee) {
    int s = csr_src[ee];
    float dd = dinv[s];
    float2 v = h2f(hp[(size_t)s * 32 + fl]);
    ax = fmaf(dd, v.x, ax);
    ay = fmaf(dd, v.y, ay);
  }
  float2 bb = ((const float2*)b)[fl];
  float2 o;
  o.x = fmaf(di, ax, bb.x);
  o.y = fmaf(di, ay, bb.y);
  ((float2*)out)[(size_t)node * 32 + fl] = o;
}

extern "C" void kernel_launch(void* const* d_in, const int* in_sizes, int n_in,
                              void* d_out, int out_size, void* d_ws, size_t ws_size,
                              hipStream_t stream) {
  const float* x  = (const float*)d_in[0];
  const int*   ei = (const int*)d_in[1];
  const float* W1 = (const float*)d_in[2];
  const float* b1 = (const float*)d_in[3];
  const float* W2 = (const float*)d_in[4];
  const float* b2 = (const float*)d_in[5];
  float* out = (float*)d_out;

  const int N = in_sizes[0] / 128;   // 50000
  const int E = in_sizes[1] / 2;     // 800000
  const int NBUCK = (N + BSIZE - 1) >> BSHIFT;   // 391
  const int NCHUNK = (E + CHUNK - 1) / CHUNK;    // 196

  char* w = (char*)d_ws;
  size_t off = 0;
  auto alloc = [&](size_t bytes) -> void* {
    void* p = w + off;
    off = (off + bytes + 511) & ~(size_t)511;
    return p;
  };
  int*       gh      = (int*)alloc((size_t)NBUCK * NCHUNK * 4);
  int*       gbase   = (int*)alloc((size_t)NBUCK * NCHUNK * 4);
  int*       totals  = (int*)alloc((size_t)NBUCK * 4);
  int*       bstart  = (int*)alloc((size_t)(NBUCK + 1) * 4);
  int*       tmp     = (int*)alloc((size_t)E * 4);
  int*       offsets = (int*)alloc((size_t)(N + 1) * 4);
  float*     dinv    = (float*)alloc((size_t)N * 4);
  int*       csr_src = (int*)alloc((size_t)E * 4);
  _Float16*  pW      = (_Float16*)alloc(24576 * 2);            // W1|W2 packs
  _Float16*  h1      = (_Float16*)alloc((size_t)N * 128 * 2);  // fp16, unscaled
  _Float16*  y       = (_Float16*)alloc((size_t)N * 128 * 2);  // fp16 (relu out)
  _Float16*  h2      = (_Float16*)alloc((size_t)N * 64 * 2);   // fp16, unscaled

  const int GB = (N + 63) / 64;   // 782
  const int AB = (N + 7) / 8;     // 6250 (8 nodes/block, 2 per wave)

  prep_k<<<96, 256, 0, stream>>>(W1, W2, pW, totals, NBUCK);
  gemm1_hist_k<<<GB + NCHUNK, 256, 0, stream>>>(x, pW, h1, ei, gh, totals,
                                                N, E, GB, NCHUNK, NBUCK);
  scanrow_k<<<NBUCK, 256, 0, stream>>>(gh, totals, gbase, bstart, offsets,
                                       NCHUNK, NBUCK, N, E);
  part_k<<<NCHUNK, 256, 0, stream>>>(ei, gbase, tmp, E, NCHUNK, NBUCK);
  bucket_k<<<NBUCK, 256, 0, stream>>>(tmp, bstart, csr_src, offsets, dinv, N);

  agg1_k<<<AB, 256, 0, stream>>>((const uint2*)h1, dinv, offsets, csr_src, b1,
                                 (uint2*)y, N);
  gemm2_k<<<GB, 256, 0, stream>>>(y, pW + 16384, h2, N);
  agg2_k<<<AB, 256, 0, stream>>>((const uint*)h2, dinv, offsets, csr_src, b2, out, N);
}